// Round 3
// 213.996 us; speedup vs baseline: 1.1794x; 1.1794x over previous
//
#include <hip/hip_runtime.h>
#include <hip/hip_bf16.h>
#include <math.h>

// Problem constants
#define BB 16
#define NN 4096
#define CC 256
#define NC 768     // 3*C
#define MTOT (BB * NN)   // 65536 tokens

typedef __attribute__((ext_vector_type(8))) __bf16 bf16x8;
typedef __attribute__((ext_vector_type(4))) float f32x4;

__device__ __forceinline__ unsigned short f2bf(float f) {
    union { float f; unsigned int u; } v; v.f = f;
    unsigned int r = (v.u + 0x7FFFu + ((v.u >> 16) & 1u)) >> 16;
    return (unsigned short)r;
}
__device__ __forceinline__ float bf2f(unsigned short b) {
    union { unsigned int u; float f; } v; v.u = ((unsigned int)b) << 16;
    return v.f;
}

#define GL16(gp, lp) \
    __builtin_amdgcn_global_load_lds((const __attribute__((address_space(1))) void*)(gp), \
                                     (__attribute__((address_space(3))) void*)(lp), 16, 0, 0)

// ---------------------------------------------------------------------------
// m97-style GEMM core for the tiny weight-prep GEMMs (K=256).  (unchanged)
// ---------------------------------------------------------------------------
template<int KDIM>
__device__ __forceinline__ void gemm_tile(const unsigned short* __restrict__ A,
                                          const unsigned short* __restrict__ Bt,
                                          int bm, int bn,
                                          unsigned short* As, unsigned short* Bs,
                                          f32x4 (&acc)[4][4]) {
    const int tid = threadIdx.x;
    const int lane = tid & 63;
    const int wave = tid >> 6;
    const int q = lane >> 4;
    const int r16 = lane & 15;
    const int wm = (wave >> 1) * 64;
    const int wn = (wave & 1) * 64;

    const int e0 = tid, e1 = tid + 256;
    const int r0 = e0 >> 2, r1 = e1 >> 2;
    const int kc0 = (e0 & 3) ^ ((r0 >> 1) & 3);
    const int kc1 = (e1 & 3) ^ ((r1 >> 1) & 3);
    const unsigned short* gA0 = A + (size_t)(bm + r0) * KDIM + kc0 * 8;
    const unsigned short* gA1 = A + (size_t)(bm + r1) * KDIM + kc1 * 8;
    const unsigned short* gB0 = Bt + (size_t)(bn + r0) * KDIM + kc0 * 8;
    const unsigned short* gB1 = Bt + (size_t)(bn + r1) * KDIM + kc1 * 8;

    const int sw = (q ^ ((r16 >> 1) & 3)) * 8;

    for (int kt = 0; kt < KDIM; kt += 32) {
        if (kt) __syncthreads();
        GL16(gA0 + kt, As + e0 * 8);
        GL16(gA1 + kt, As + e1 * 8);
        GL16(gB0 + kt, Bs + e0 * 8);
        GL16(gB1 + kt, Bs + e1 * 8);
        __syncthreads();

        bf16x8 af[4], bfr[4];
#pragma unroll
        for (int mi = 0; mi < 4; ++mi)
            af[mi] = *(const bf16x8*)(As + (wm + mi * 16 + r16) * 32 + sw);
#pragma unroll
        for (int ni = 0; ni < 4; ++ni)
            bfr[ni] = *(const bf16x8*)(Bs + (wn + ni * 16 + r16) * 32 + sw);
#pragma unroll
        for (int mi = 0; mi < 4; ++mi)
#pragma unroll
            for (int ni = 0; ni < 4; ++ni)
                acc[mi][ni] = __builtin_amdgcn_mfma_f32_16x16x32_bf16(
                    af[mi], bfr[ni], acc[mi][ni], 0, 0, 0);
    }
}

// ---------------------------------------------------------------------------
// Fused converter: Wqkv -> Wqb/Wkb/Wvs (bf16), Wproj -> WpT (bf16 transposed)
// ---------------------------------------------------------------------------
__global__ __launch_bounds__(256) void conv_all(const float* __restrict__ Wqkv,
                                                const float* __restrict__ Wproj,
                                                unsigned short* __restrict__ Wqb,
                                                unsigned short* __restrict__ Wkb,
                                                unsigned short* __restrict__ Wvs,
                                                unsigned short* __restrict__ WpT) {
    int t = blockIdx.x * 256 + threadIdx.x;
    if (t < 3 * CC * NC) {
        unsigned short v = f2bf(Wqkv[t]);
        int ic = t / NC;           // i*256 + a  (input channel a)
        int col = t - ic * NC;
        if (col < 256)       Wqb[(size_t)ic * CC + col] = v;
        else if (col < 512)  Wkb[(size_t)ic * CC + col - 256] = v;
        else                 Wvs[(size_t)ic * CC + col - 512] = v;
    } else {
        int e = t - 3 * CC * NC;   // < 65536
        int g = e >> 8, c = e & 255;
        WpT[e] = f2bf(Wproj[(size_t)c * CC + g]);   // WpT[g][c] = Wproj[c][g]
    }
}

// ---------------------------------------------------------------------------
// Batched weight GEMM: z<3 -> MtY_i = scale * Wk_i Wq_i^T  (256x256)
//                      z=3 -> PtZ = (1/3) * Wproj^T x Wv   (256x768)
// ---------------------------------------------------------------------------
__global__ __launch_bounds__(256) void wgemm(const unsigned short* __restrict__ Wqb,
                                             const unsigned short* __restrict__ Wkb,
                                             const unsigned short* __restrict__ Wvs,
                                             const unsigned short* __restrict__ WpT,
                                             unsigned short* __restrict__ MtY,
                                             unsigned short* __restrict__ PtZ) {
    const int z = blockIdx.z;
    const unsigned short *A, *Bt;
    unsigned short* C;
    int nout; float mult;
    if (z < 3) {
        if (blockIdx.x >= 2) return;
        A = Wkb + z * CC * CC; Bt = Wqb + z * CC * CC; C = MtY + z * CC * CC;
        nout = CC; mult = 0.0625f;            // C^-0.5
    } else {
        A = WpT; Bt = Wvs; C = PtZ;
        nout = NC; mult = 1.0f / 3.0f;
    }

    __shared__ unsigned short As[128 * 32];
    __shared__ unsigned short Bs[128 * 32];
    f32x4 acc[4][4];
#pragma unroll
    for (int i = 0; i < 4; ++i)
#pragma unroll
        for (int j = 0; j < 4; ++j) acc[i][j] = {0.f, 0.f, 0.f, 0.f};

    gemm_tile<CC>(A, Bt, blockIdx.y * 128, blockIdx.x * 128, As, Bs, acc);

    const int lane = threadIdx.x & 63;
    const int wave = threadIdx.x >> 6;
    const int q = lane >> 4, r16 = lane & 15;
    const int wm = (wave >> 1) * 64, wn = (wave & 1) * 64;
#pragma unroll
    for (int mi = 0; mi < 4; ++mi)
#pragma unroll
        for (int ni = 0; ni < 4; ++ni) {
            int row0 = blockIdx.y * 128 + wm + mi * 16 + q * 4;
            int col = blockIdx.x * 128 + wn + ni * 16 + r16;
#pragma unroll
            for (int r = 0; r < 4; ++r)
                C[(size_t)(row0 + r) * nout + col] = f2bf(acc[mi][ni][r] * mult);
        }
}

// ---------------------------------------------------------------------------
// MEGA kernel, v2: deep-pipelined weight stream + wave-local attention.
//
// Weight stream: 96 global stages (3 dil x [16 M-stages + 16 P-stages]),
//   each 8 KB = 2 x GL16/thread, held in bstage[4] ring. Loads issued 3
//   stages ahead; consume sync is  s_waitcnt vmcnt(4) ; raw s_barrier
//   (never vmcnt(0) in the loop -> prefetch stays in flight across
//   barriers, T3/T4). 8 MFMA per wave per barrier.
//
// Wave-local attention: each wave owns 16 tokens. Per cq-slice, Y-slice
//   goes regs -> yseg (16x72, wave-private) -> A-frag; logits = 6 MFMAs
//   vs shifted-x B-frags (diag of 16x16); softmax on diagonal lanes ->
//   wsm; z built on-the-fly in P3 from (w0,w1,w2) and xbuf. No ybuf, no
//   cross-wave barriers in attention.
//
// LDS: xbuf 70x264 (36960) + bstage 4x8KB (32768) + yseg 4x16x72 (9216)
//      + wsm 64x4 f32 (1024) = 79968 B -> 2 blocks/CU.
// ---------------------------------------------------------------------------
__global__ __launch_bounds__(256, 2) void mega(const float* __restrict__ xf,
                                               const unsigned short* __restrict__ MtY,
                                               const unsigned short* __restrict__ PtZ,
                                               const float* __restrict__ bias,
                                               float* __restrict__ out) {
    __shared__ __align__(16) unsigned short xbuf[70 * 264];
    __shared__ __align__(16) unsigned short bstage[4 * 4096];
    __shared__ __align__(16) unsigned short yseg[4 * 16 * 72];
    __shared__ __align__(16) float wsm[64 * 4];

    const int tid = threadIdx.x;
    const int lane = tid & 63;
    const int wave = tid >> 6;
    const int q = lane >> 4;
    const int r16 = lane & 15;
    const int t0 = blockIdx.x * 64;

    // per-thread staging source precompute (conflict swizzle as before)
    const int colA = tid >> 2;
    const int kcA = (tid & 3) ^ ((colA >> 1) & 3);
    const unsigned short* mBase  = MtY + (size_t)colA * CC + kcA * 8;
    const unsigned short* pBase0 = PtZ + (size_t)colA * NC + kcA * 8;
    const unsigned short* pBase1 = PtZ + (size_t)(colA + 64) * NC + kcA * 8;

    // Stage gs (0..95): dil i2 = gs>>5; r = gs&31.
    //  r<16 : M-stage (cq=r>>2, ktp=r&3): 64 Y-cols x 64 k, two 32-k halves.
    //  r>=16: P-stage (kt=(r-16)>>1, cqp=(r-16)&1): 128 out-cols x 32 k.
    auto issue_stage = [&](int gs) {
        if (gs >= 96) return;
        unsigned short* dst = bstage + (gs & 3) * 4096 + tid * 8;
        const int i2 = gs >> 5;
        const int r = gs & 31;
        if (r < 16) {
            const unsigned short* src =
                mBase + (size_t)(i2 * 256 + (r >> 2) * 64) * CC + (r & 3) * 64;
            GL16(src, dst);                 // kt2 = 0
            GL16(src + 32, dst + 2048);     // kt2 = 1
        } else {
            const int r2 = r - 16;
            const size_t off = (size_t)(r2 & 1) * (128 * NC) + i2 * 256 + (r2 >> 1) * 32;
            GL16(pBase0 + off, dst);            // cols 0..63 of the 128-half
            GL16(pBase1 + off, dst + 2048);     // cols 64..127
        }
    };

    // prologue: first 3 stages fly while x is staged
    issue_stage(0); issue_stage(1); issue_stage(2);

    // ---- stage x rows [t0-3, t0+67) fp32 -> bf16 LDS (clamped; masked later)
    for (int it = 0; it < 9; ++it) {
        int e = it * 256 + tid;          // 70 rows * 32 chunks = 2240
        if (e < 2240) {
            int rr = e >> 5, c = e & 31;
            int gr = t0 - 3 + rr;
            gr = gr < 0 ? 0 : (gr > MTOT - 1 ? MTOT - 1 : gr);
            const float* xp = xf + (size_t)gr * CC + c * 8;
            float4 a = *(const float4*)xp;
            float4 b = *(const float4*)(xp + 4);
            unsigned short p[8];
            p[0] = f2bf(a.x); p[1] = f2bf(a.y); p[2] = f2bf(a.z); p[3] = f2bf(a.w);
            p[4] = f2bf(b.x); p[5] = f2bf(b.y); p[6] = f2bf(b.z); p[7] = f2bf(b.w);
            *(float4*)(xbuf + rr * 264 + c * 8) = *(const float4*)p;
        }
    }
    __syncthreads();   // drains x loads AND stages 0-2 (one-time vmcnt(0))

    // persistent A-fragments: wave's 16 tokens (rows 3+wave*16+r16)
    bf16x8 af[8];
#pragma unroll
    for (int kt = 0; kt < 8; ++kt)
        af[kt] = *(const bf16x8*)(xbuf + (3 + wave * 16 + r16) * 264 + kt * 32 + q * 8);

    f32x4 oacc[16];
#pragma unroll
    for (int j = 0; j < 16; ++j) oacc[j] = {0.f, 0.f, 0.f, 0.f};

    const int fragsw = q ^ ((r16 >> 1) & 3);   // fragment k-chunk swizzle
    int gctr = 3;    // next stage to issue (3-ahead invariant: gctr == sctr+3)
    int sctr = 0;    // stage being consumed

#pragma unroll 1
    for (int i = 0; i < 3; ++i) {
        const int dil = i + 1;
        f32x4 lacc[3];
#pragma unroll
        for (int j = 0; j < 3; ++j) lacc[j] = {0.f, 0.f, 0.f, 0.f};

        // ================= Phase 1: Y = x @ M_i^T, logits via MFMA ==========
#pragma unroll
        for (int cq = 0; cq < 4; ++cq) {
            f32x4 yacc[4];
#pragma unroll
            for (int nf = 0; nf < 4; ++nf) yacc[nf] = {0.f, 0.f, 0.f, 0.f};
#pragma unroll
            for (int ktp = 0; ktp < 4; ++ktp) {
                asm volatile("s_waitcnt vmcnt(4)" ::: "memory");  // own stage-s pair done
                __builtin_amdgcn_s_barrier();                     // everyone's done
                __builtin_amdgcn_sched_barrier(0);
                issue_stage(gctr); ++gctr;                        // overwrite buf (s-1)&3
                const unsigned short* bp = bstage + (sctr & 3) * 4096;
                ++sctr;
                __builtin_amdgcn_s_setprio(1);
#pragma unroll
                for (int kt2 = 0; kt2 < 2; ++kt2)
#pragma unroll
                    for (int nf = 0; nf < 4; ++nf) {
                        bf16x8 b = *(const bf16x8*)(bp + kt2 * 2048 +
                                        ((nf * 16 + r16) * 4 + fragsw) * 8);
                        yacc[nf] = __builtin_amdgcn_mfma_f32_16x16x32_bf16(
                            af[ktp * 2 + kt2], b, yacc[nf], 0, 0, 0);
                    }
                __builtin_amdgcn_s_setprio(0);
            }
            // Y-slice (16 tokens x 64 ch) -> wave-private yseg, then 6 logit MFMAs
            unsigned short* ys = yseg + wave * (16 * 72);
#pragma unroll
            for (int nf = 0; nf < 4; ++nf)
#pragma unroll
                for (int rr = 0; rr < 4; ++rr)
                    ys[(q * 4 + rr) * 72 + nf * 16 + r16] = f2bf(yacc[nf][rr]);
            asm volatile("s_waitcnt lgkmcnt(0)" ::: "memory");    // writes visible in-wave
            __builtin_amdgcn_sched_barrier(0);
            bf16x8 ya0 = *(const bf16x8*)(ys + r16 * 72 + q * 8);
            bf16x8 ya1 = *(const bf16x8*)(ys + r16 * 72 + 32 + q * 8);
#pragma unroll
            for (int j = 0; j < 3; ++j) {
                const unsigned short* xr =
                    xbuf + (3 + wave * 16 + r16 + (j - 1) * dil) * 264 + cq * 64 + q * 8;
                bf16x8 xb0 = *(const bf16x8*)xr;
                bf16x8 xb1 = *(const bf16x8*)(xr + 32);
                lacc[j] = __builtin_amdgcn_mfma_f32_16x16x32_bf16(ya0, xb0, lacc[j], 0, 0, 0);
                lacc[j] = __builtin_amdgcn_mfma_f32_16x16x32_bf16(ya1, xb1, lacc[j], 0, 0, 0);
            }
        }

        // ============ softmax: diagonal lanes (q == r16>>2) own token r16 ====
        {
            const int rr = r16 & 3;
            float l0 = rr == 0 ? lacc[0][0] : rr == 1 ? lacc[0][1] : rr == 2 ? lacc[0][2] : lacc[0][3];
            float l1 = rr == 0 ? lacc[1][0] : rr == 1 ? lacc[1][1] : rr == 2 ? lacc[1][2] : lacc[1][3];
            float l2 = rr == 0 ? lacc[2][0] : rr == 1 ? lacc[2][1] : rr == 2 ? lacc[2][2] : lacc[2][3];
            const int ns = (t0 + wave * 16 + r16) & (NN - 1);
            const bool vlo = ns >= dil;
            const bool vhi = ns + dil < NN;
            l0 = vlo ? l0 : 0.f;      // zero-logit padding (matches reference)
            l2 = vhi ? l2 : 0.f;
            float mx = fmaxf(l0, fmaxf(l1, l2));
            float e0 = __expf(l0 - mx), e1 = __expf(l1 - mx), e2 = __expf(l2 - mx);
            float inv = 1.0f / (e0 + e1 + e2);
            if (q == (r16 >> 2)) {
                float* wq = wsm + (wave * 16 + r16) * 4;
                wq[0] = vlo ? e0 * inv : 0.f;
                wq[1] = e1 * inv;
                wq[2] = vhi ? e2 * inv : 0.f;
            }
        }
        asm volatile("s_waitcnt lgkmcnt(0)" ::: "memory");
        __builtin_amdgcn_sched_barrier(0);
        const float* wp = wsm + (wave * 16 + r16) * 4;
        const float w0 = wp[0], w1 = wp[1], w2 = wp[2];

        // ================= Phase 3: oacc += z @ P_i  (z built on the fly) ===
#pragma unroll
        for (int kt = 0; kt < 8; ++kt) {
            const unsigned short* xr1 =
                xbuf + (3 + wave * 16 + r16) * 264 + kt * 32 + q * 8;
            bf16x8 a0 = *(const bf16x8*)(xr1 - dil * 264);
            bf16x8 a1 = *(const bf16x8*)(xr1);
            bf16x8 a2 = *(const bf16x8*)(xr1 + dil * 264);
            const unsigned short* u0 = (const unsigned short*)&a0;
            const unsigned short* u1 = (const unsigned short*)&a1;
            const unsigned short* u2 = (const unsigned short*)&a2;
            union { unsigned short s[8]; bf16x8 v; } za;
#pragma unroll
            for (int e = 0; e < 8; ++e)
                za.s[e] = f2bf(w0 * bf2f(u0[e]) + w1 * bf2f(u1[e]) + w2 * bf2f(u2[e]));
#pragma unroll
            for (int cqp = 0; cqp < 2; ++cqp) {
                asm volatile("s_waitcnt vmcnt(4)" ::: "memory");
                __builtin_amdgcn_s_barrier();
                __builtin_amdgcn_sched_barrier(0);
                issue_stage(gctr); ++gctr;
                const unsigned short* bp = bstage + (sctr & 3) * 4096;
                ++sctr;
                __builtin_amdgcn_s_setprio(1);
#pragma unroll
                for (int cq2 = 0; cq2 < 2; ++cq2)
#pragma unroll
                    for (int nf = 0; nf < 4; ++nf) {
                        const int col = cq2 * 64 + nf * 16 + r16;
                        bf16x8 b = *(const bf16x8*)(bp + (col * 4 + fragsw) * 8);
                        oacc[(cqp * 2 + cq2) * 4 + nf] =
                            __builtin_amdgcn_mfma_f32_16x16x32_bf16(
                                za.v, b, oacc[(cqp * 2 + cq2) * 4 + nf], 0, 0, 0);
                    }
                __builtin_amdgcn_s_setprio(0);
            }
        }
    }

    // ================= Epilogue: out = oacc + bias =================
#pragma unroll
    for (int cq = 0; cq < 4; ++cq)
#pragma unroll
        for (int nf = 0; nf < 4; ++nf) {
            int gc = cq * 64 + nf * 16 + r16;
            float bc = bias[gc];
            f32x4 v = oacc[cq * 4 + nf];
#pragma unroll
            for (int r = 0; r < 4; ++r)
                out[(size_t)(t0 + wave * 16 + q * 4 + r) * CC + gc] = v[r] + bc;
        }
}

// ---------------------------------------------------------------------------
extern "C" void kernel_launch(void* const* d_in, const int* in_sizes, int n_in,
                              void* d_out, int out_size, void* d_ws, size_t ws_size,
                              hipStream_t stream) {
    const float* x = (const float*)d_in[0];      // (16, 4096, 256)
    const float* Wqkv = (const float*)d_in[1];   // (3, 256, 768)
    const float* Wproj = (const float*)d_in[2];  // (256, 256)
    const float* bproj = (const float*)d_in[3];  // (256,)
    float* out = (float*)d_out;                  // (16, 4096, 256)

    unsigned short* Wqb = (unsigned short*)d_ws;           // 3*256*256
    unsigned short* Wkb = Wqb + (size_t)3 * CC * CC;
    unsigned short* Wvs = Wkb + (size_t)3 * CC * CC;       // (768,256): [(i,a)][c]
    unsigned short* WpT = Wvs + (size_t)3 * CC * CC;       // (256,256): [g][c]
    unsigned short* MtY = WpT + (size_t)CC * CC;           // (768,256): [(i,b)][a]
    unsigned short* PtZ = MtY + (size_t)NC * CC;           // (256,768): [g][(i,a)]

    conv_all<<<(3 * CC * NC + CC * CC) / 256, 256, 0, stream>>>(
        Wqkv, Wproj, Wqb, Wkb, Wvs, WpT);
    wgemm<<<dim3(6, 2, 4), 256, 0, stream>>>(Wqb, Wkb, Wvs, WpT, MtY, PtZ);
    mega<<<MTOT / 64, 256, 0, stream>>>(x, MtY, PtZ, bproj, out);
}